// Round 2
// baseline (870.942 us; speedup 1.0000x reference)
//
#include <hip/hip_runtime.h>

constexpr int NODE = 128;
constexpr int HID  = 64;

// --- W1 [NODE][HID] -> W1T [HID][NODE] so each hidden unit's weights are contiguous
__global__ void transpose_w1_kernel(const float* __restrict__ w1, float* __restrict__ w1t) {
    int t = blockIdx.x * blockDim.x + threadIdx.x;
    if (t < NODE * HID) {
        int j = t / NODE;
        int k = t - j * NODE;
        w1t[j * NODE + k] = w1[k * HID + j];
    }
}

// --- mass-weighted centroid accumulation with wave-segmented pre-reduction.
// batch is sorted, so equal keys are adjacent: segmented inclusive scan within
// the wave, then one atomic per (segment x wave).
__global__ void centroid_accum_kernel(const float* __restrict__ pos,
                                      const int* __restrict__ at_no,
                                      const int* __restrict__ batch,
                                      const float* __restrict__ masses,
                                      float* __restrict__ num,
                                      float* __restrict__ den,
                                      int n) {
    int i = blockIdx.x * blockDim.x + threadIdx.x;
    int lane = threadIdx.x & 63;

    int b = -1;
    float m = 0.f, wx = 0.f, wy = 0.f, wz = 0.f;
    if (i < n) {
        b = batch[i];
        m = masses[at_no[i]];
        wx = m * pos[3 * i + 0];
        wy = m * pos[3 * i + 1];
        wz = m * pos[3 * i + 2];
    }
    // segmented inclusive scan by key b
    #pragma unroll
    for (int off = 1; off < 64; off <<= 1) {
        int   ob = __shfl_up(b, off);
        float om = __shfl_up(m, off);
        float ox = __shfl_up(wx, off);
        float oy = __shfl_up(wy, off);
        float oz = __shfl_up(wz, off);
        if (lane >= off && ob == b) { m += om; wx += ox; wy += oy; wz += oz; }
    }
    int nxt = __shfl_down(b, 1);
    bool last = (lane == 63) || (nxt != b);
    if (last && b >= 0) {
        atomicAdd(&den[b], m);
        atomicAdd(&num[3 * b + 0], wx);
        atomicAdd(&num[3 * b + 1], wy);
        atomicAdd(&num[3 * b + 2], wz);
    }
}

// --- centroids = num / den (in place)
__global__ void centroid_div_kernel(float* __restrict__ num,
                                    const float* __restrict__ den,
                                    int nb) {
    int b = blockIdx.x * blockDim.x + threadIdx.x;
    if (b >= nb) return;
    float inv = 1.0f / den[b];
    num[3 * b + 0] *= inv;
    num[3 * b + 1] *= inv;
    num[3 * b + 2] *= inv;
}

// --- main: per-atom MLP (128->64 silu ->1) * squared distance to centroid.
// One lane = one atom. 64 hidden accumulators live in VGPRs; x streamed in
// 16-float register tiles (each x element loaded from memory exactly once).
// Weight addresses are wave-uniform -> scalar loads -> free SGPR operand on
// v_fma_f32. Output pre-reduced with a wave-segmented scan (batch sorted).
__global__ __launch_bounds__(256, 4) void spatial_main_kernel(
    const float* __restrict__ x,
    const float* __restrict__ pos,
    const int* __restrict__ batch,
    const float* __restrict__ cent,   // [nb*3], already divided
    const float* __restrict__ w1t,    // [HID*NODE]
    const float* __restrict__ b1,     // [HID]
    const float* __restrict__ w2,     // [HID]
    const float* __restrict__ b2,     // [1]
    float* __restrict__ out,          // [nb]
    int n) {
    int i = blockIdx.x * blockDim.x + threadIdx.x;
    int lane = threadIdx.x & 63;
    int idx = i < n ? i : (n - 1);    // tail lanes compute garbage, masked later

    float acc[HID];
    #pragma unroll
    for (int j = 0; j < HID; ++j) acc[j] = b1[j];

    const float4* xp = reinterpret_cast<const float4*>(x + (size_t)idx * NODE);
    #pragma unroll 1
    for (int kt = 0; kt < NODE / 16; ++kt) {      // 8 tiles of 16 floats
        float xr[16];
        #pragma unroll
        for (int q = 0; q < 4; ++q) {
            float4 v = xp[kt * 4 + q];
            xr[4 * q + 0] = v.x;
            xr[4 * q + 1] = v.y;
            xr[4 * q + 2] = v.z;
            xr[4 * q + 3] = v.w;
        }
        const float* __restrict__ wbase = w1t + kt * 16;   // wave-uniform
        #pragma unroll
        for (int j = 0; j < HID; ++j) {
            const float* __restrict__ w = wbase + j * NODE;
            #pragma unroll
            for (int k = 0; k < 16; ++k)
                acc[j] = fmaf(xr[k], w[k], acc[j]);
        }
    }

    float out_acc = 0.0f;
    #pragma unroll
    for (int j = 0; j < HID; ++j) {
        float s = acc[j];
        float h = s / (1.0f + __expf(-s));   // silu
        out_acc = fmaf(h, w2[j], out_acc);
    }
    out_acc += b2[0];

    int b = i < n ? batch[idx] : -1;
    float v = 0.0f;
    if (i < n) {
        float cx = cent[3 * b + 0];
        float cy = cent[3 * b + 1];
        float cz = cent[3 * b + 2];
        float dx = pos[3 * idx + 0] - cx;
        float dy = pos[3 * idx + 1] - cy;
        float dz = pos[3 * idx + 2] - cz;
        v = out_acc * (dx * dx + dy * dy + dz * dz);
    }

    // wave-segmented inclusive scan by key b, one atomic per segment end
    #pragma unroll
    for (int off = 1; off < 64; off <<= 1) {
        int   ob = __shfl_up(b, off);
        float ov = __shfl_up(v, off);
        if (lane >= off && ob == b) v += ov;
    }
    int nxt = __shfl_down(b, 1);
    bool last = (lane == 63) || (nxt != b);
    if (last && b >= 0) atomicAdd(&out[b], v);
}

extern "C" void kernel_launch(void* const* d_in, const int* in_sizes, int n_in,
                              void* d_out, int out_size, void* d_ws, size_t ws_size,
                              hipStream_t stream) {
    const float* x      = (const float*)d_in[0];   // [N,128]
    const float* pos    = (const float*)d_in[1];   // [N,3]
    const int*   at_no  = (const int*)d_in[2];     // [N]
    const int*   batch  = (const int*)d_in[3];     // [N]
    const float* masses = (const float*)d_in[4];   // [119]
    const float* W1     = (const float*)d_in[5];   // [128,64]
    const float* b1     = (const float*)d_in[6];   // [64]
    const float* W2     = (const float*)d_in[7];   // [64,1]
    const float* b2     = (const float*)d_in[8];   // [1]

    int n  = in_sizes[2];   // N atoms
    int nb = out_size;      // B molecules

    float* out = (float*)d_out;
    float* ws  = (float*)d_ws;
    float* num = ws;                  // [nb*3]
    float* den = ws + 3 * (size_t)nb; // [nb]
    float* w1t = ws + 4 * (size_t)nb; // [HID*NODE]

    hipMemsetAsync(num, 0, (size_t)4 * nb * sizeof(float), stream);
    hipMemsetAsync(d_out, 0, (size_t)nb * sizeof(float), stream);

    transpose_w1_kernel<<<(NODE * HID + 255) / 256, 256, 0, stream>>>(W1, w1t);
    centroid_accum_kernel<<<(n + 255) / 256, 256, 0, stream>>>(pos, at_no, batch, masses,
                                                               num, den, n);
    centroid_div_kernel<<<(nb + 255) / 256, 256, 0, stream>>>(num, den, nb);
    spatial_main_kernel<<<(n + 255) / 256, 256, 0, stream>>>(x, pos, batch, num, w1t,
                                                             b1, W2, b2, out, n);
}

// Round 3
// 121.921 us; speedup vs baseline: 7.1435x; 7.1435x over previous
//
#include <hip/hip_runtime.h>

constexpr int NODE = 128;
constexpr int HID  = 64;

typedef __attribute__((ext_vector_type(8))) __bf16 bf16x8;
typedef __attribute__((ext_vector_type(8))) short  short8;
typedef __attribute__((ext_vector_type(4))) float  f32x4;

union frag_u { short8 s; bf16x8 b; };

static __device__ __forceinline__ unsigned short f2bf(float f) {
    unsigned u = __builtin_bit_cast(unsigned, f);
    unsigned r = (u + 0x7FFFu + ((u >> 16) & 1u)) >> 16;   // RNE
    return (unsigned short)r;
}

// --- W1 [128][64] f32 -> pre-swizzled bf16 B-fragments for mfma_f32_16x16x32_bf16.
// Element e = ((s*4+t)*64 + lane)*8 + j  holds  B[k = s*32 + (lane>>4)*8 + j][col = t*16 + (lane&15)]
__global__ void prep_w1_kernel(const float* __restrict__ w1, unsigned short* __restrict__ w1b) {
    int e = blockIdx.x * blockDim.x + threadIdx.x;
    if (e >= 4 * 4 * 64 * 8) return;
    int j = e & 7;
    int l = (e >> 3) & 63;
    int t = (e >> 9) & 3;
    int s = (e >> 11) & 3;
    int k   = s * 32 + (l >> 4) * 8 + j;
    int col = t * 16 + (l & 15);
    w1b[e] = f2bf(w1[k * HID + col]);
}

// --- mass-weighted centroid accumulation with wave-segmented pre-reduction (batch sorted)
__global__ void centroid_accum_kernel(const float* __restrict__ pos,
                                      const int* __restrict__ at_no,
                                      const int* __restrict__ batch,
                                      const float* __restrict__ masses,
                                      float* __restrict__ num,
                                      float* __restrict__ den,
                                      int n) {
    int i = blockIdx.x * blockDim.x + threadIdx.x;
    int lane = threadIdx.x & 63;

    int b = -1;
    float m = 0.f, wx = 0.f, wy = 0.f, wz = 0.f;
    if (i < n) {
        b = batch[i];
        m = masses[at_no[i]];
        wx = m * pos[3 * i + 0];
        wy = m * pos[3 * i + 1];
        wz = m * pos[3 * i + 2];
    }
    #pragma unroll
    for (int off = 1; off < 64; off <<= 1) {
        int   ob = __shfl_up(b, off);
        float om = __shfl_up(m, off);
        float ox = __shfl_up(wx, off);
        float oy = __shfl_up(wy, off);
        float oz = __shfl_up(wz, off);
        if (lane >= off && ob == b) { m += om; wx += ox; wy += oy; wz += oz; }
    }
    int nxt = __shfl_down(b, 1);
    bool last = (lane == 63) || (nxt != b);
    if (last && b >= 0) {
        atomicAdd(&den[b], m);
        atomicAdd(&num[3 * b + 0], wx);
        atomicAdd(&num[3 * b + 1], wy);
        atomicAdd(&num[3 * b + 2], wz);
    }
}

__global__ void centroid_div_kernel(float* __restrict__ num,
                                    const float* __restrict__ den,
                                    int nb) {
    int b = blockIdx.x * blockDim.x + threadIdx.x;
    if (b >= nb) return;
    float inv = 1.0f / den[b];
    num[3 * b + 0] *= inv;
    num[3 * b + 1] *= inv;
    num[3 * b + 2] *= inv;
}

// --- main: bf16 MFMA MLP (128->64, silu, ->1) * |pos-centroid|^2, scatter to out.
// One wave = one 16-atom tile (grid-stride). A: x rows cvt'd to bf16 on the fly.
// B: W1 fragments staged in 16 KB LDS, read as short8 (ds_read_b128, conflict-free).
// D layout (m89/m91): col = lane&15 (hidden), row = (lane>>4)*4 + reg (atom).
__global__ __launch_bounds__(256, 4) void spatial_main_kernel(
    const float* __restrict__ x,
    const float* __restrict__ pos,
    const int* __restrict__ batch,
    const float* __restrict__ cent,          // [nb*3], already divided
    const unsigned short* __restrict__ w1b,  // [8192] pre-swizzled bf16 fragments
    const float* __restrict__ b1,            // [64]
    const float* __restrict__ w2,            // [64]
    const float* __restrict__ b2,            // [1]
    float* __restrict__ out,                 // [nb]
    int n) {
    __shared__ short8 lds_b[1024];           // [s][t][lane] fragments, 16 KB

    int tid = threadIdx.x;
    const short8* gb = reinterpret_cast<const short8*>(w1b);
    #pragma unroll
    for (int q = 0; q < 4; ++q) lds_b[q * 256 + tid] = gb[q * 256 + tid];
    __syncthreads();

    int lane = tid & 63;
    int row  = lane & 15;        // A-row / atom-within-tile for input
    int half = lane >> 4;        // k-chunk group
    int gwave = blockIdx.x * (blockDim.x >> 6) + (tid >> 6);
    int nwave = gridDim.x * (blockDim.x >> 6);

    // per-lane epilogue constants: hidden unit hid = t*16 + (lane&15)
    float b1t[4], w2t[4];
    #pragma unroll
    for (int t = 0; t < 4; ++t) {
        b1t[t] = b1[t * 16 + row];
        w2t[t] = w2[t * 16 + row];
    }
    float b2v = b2[0];

    int ntiles = (n + 15) >> 4;
    for (int tile = gwave; tile < ntiles; tile += nwave) {
        int base = tile << 4;
        int atom = base + row;
        int aL = atom < n ? atom : (n - 1);    // clamped for loads; masked later
        const float4* xp = reinterpret_cast<const float4*>(x) + (size_t)aL * 32 + half * 2;

        f32x4 c[4];
        #pragma unroll
        for (int t = 0; t < 4; ++t) c[t] = (f32x4){0.f, 0.f, 0.f, 0.f};

        #pragma unroll
        for (int s = 0; s < 4; ++s) {
            float4 v0 = xp[s * 8 + 0];
            float4 v1 = xp[s * 8 + 1];
            frag_u a;
            a.s[0] = (short)f2bf(v0.x);
            a.s[1] = (short)f2bf(v0.y);
            a.s[2] = (short)f2bf(v0.z);
            a.s[3] = (short)f2bf(v0.w);
            a.s[4] = (short)f2bf(v1.x);
            a.s[5] = (short)f2bf(v1.y);
            a.s[6] = (short)f2bf(v1.z);
            a.s[7] = (short)f2bf(v1.w);
            #pragma unroll
            for (int t = 0; t < 4; ++t) {
                frag_u bu;
                bu.s = lds_b[(s * 4 + t) * 64 + lane];
                c[t] = __builtin_amdgcn_mfma_f32_16x16x32_bf16(a.b, bu.b, c[t], 0, 0, 0);
            }
        }

        // epilogue: silu + w2-weighted reduce over hidden (cols), per output row r
        float p[4];
        #pragma unroll
        for (int r = 0; r < 4; ++r) {
            float sum = 0.f;
            #pragma unroll
            for (int t = 0; t < 4; ++t) {
                float sv = c[t][r] + b1t[t];
                float h  = sv / (1.0f + __expf(-sv));   // silu
                sum = fmaf(h, w2t[t], sum);
            }
            sum += __shfl_xor(sum, 1);
            sum += __shfl_xor(sum, 2);
            sum += __shfl_xor(sum, 4);
            sum += __shfl_xor(sum, 8);
            p[r] = sum + b2v;
        }

        // redistribute: lane q (q<16) takes atom base+q from group q>>2, reg q&3
        int q = lane & 15;
        int srcl = (q >> 2) << 4;
        float s0 = __shfl(p[0], srcl);
        float s1 = __shfl(p[1], srcl);
        float s2 = __shfl(p[2], srcl);
        float s3 = __shfl(p[3], srcl);
        float sa = (q & 1) ? s1 : s0;
        float sb = (q & 1) ? s3 : s2;
        float mlp = (q & 2) ? sb : sa;

        int a = base + q;
        int bkey = -1;
        float val = 0.f;
        if (lane < 16 && a < n) {
            bkey = batch[a];
            float cx = cent[3 * bkey + 0];
            float cy = cent[3 * bkey + 1];
            float cz = cent[3 * bkey + 2];
            float dx = pos[3 * a + 0] - cx;
            float dy = pos[3 * a + 1] - cy;
            float dz = pos[3 * a + 2] - cz;
            val = mlp * (dx * dx + dy * dy + dz * dz);
        }
        // segmented scan (segments live within lanes 0..15; inactive keys = -1)
        #pragma unroll
        for (int off = 1; off < 16; off <<= 1) {
            int   ob = __shfl_up(bkey, off);
            float ov = __shfl_up(val, off);
            if (lane >= off && ob == bkey) val += ov;
        }
        int nxt = __shfl_down(bkey, 1);
        bool lastl = (lane == 63) || (nxt != bkey);
        if (bkey >= 0 && lastl) atomicAdd(&out[bkey], val);
    }
}

extern "C" void kernel_launch(void* const* d_in, const int* in_sizes, int n_in,
                              void* d_out, int out_size, void* d_ws, size_t ws_size,
                              hipStream_t stream) {
    const float* x      = (const float*)d_in[0];   // [N,128]
    const float* pos    = (const float*)d_in[1];   // [N,3]
    const int*   at_no  = (const int*)d_in[2];     // [N]
    const int*   batch  = (const int*)d_in[3];     // [N]
    const float* masses = (const float*)d_in[4];   // [119]
    const float* W1     = (const float*)d_in[5];   // [128,64]
    const float* b1     = (const float*)d_in[6];   // [64]
    const float* W2     = (const float*)d_in[7];   // [64,1]
    const float* b2     = (const float*)d_in[8];   // [1]

    int n  = in_sizes[2];   // N atoms
    int nb = out_size;      // B molecules

    float* out = (float*)d_out;
    float* ws  = (float*)d_ws;
    float* num = ws;                   // [nb*3]
    float* den = ws + 3 * (size_t)nb;  // [nb]
    unsigned short* w1b = (unsigned short*)(ws + 4 * (size_t)nb);  // [8192] bf16, 16B-aligned

    hipMemsetAsync(num, 0, (size_t)4 * nb * sizeof(float), stream);
    hipMemsetAsync(d_out, 0, (size_t)nb * sizeof(float), stream);

    prep_w1_kernel<<<32, 256, 0, stream>>>(W1, w1b);
    centroid_accum_kernel<<<(n + 255) / 256, 256, 0, stream>>>(pos, at_no, batch, masses,
                                                               num, den, n);
    centroid_div_kernel<<<(nb + 255) / 256, 256, 0, stream>>>(num, den, nb);
    spatial_main_kernel<<<4096, 256, 0, stream>>>(x, pos, batch, num, w1b,
                                                  b1, W2, b2, out, n);
}